// Round 10
// baseline (145.206 us; speedup 1.0000x reference)
//
#include <hip/hip_runtime.h>

// HistoLoss: B=1024, T=256, C=16, NB=64; TC=4096; x flat = [b][tc]
//
// ROUND-10 = DISCRIMINATING SLOPE TEST (R9 structure, 4x redundant inner
// passes, counts >>2 at the end -> bit-identical output).
// Why: k1+k2 inferred ~30us (anchors R1/R5) but first-principles says ~5us;
// four neutral rounds (R4/R6/R7/R9) prove inner-loop inst count is NOT the
// pin. 4x work gives: (a) slope -> true k1 compute = (total-91.7)/3;
// (b) if compute-bound, k1 rises above the 43.5us fill cutoff and finally
// shows direct VALUBusy/Occupancy counters in top-5.
//   H1 (slow v_pk / issue ceiling): total ~150-165, k1 in top-5, VALU>80%.
//   H2 (harness floor ~84us, k1 already ~5us): total ~100-112, k1 absent.
//
// Inner loop (inline asm, 5 inst / 2 indicators, guaranteed):
//   v_pk_add_f16 d,x2,-l2 ; v_and 0x7fff7fff ; v_pk_add_f16 d,d,-h2
//   v_pk_lshrrev_b16 d,15 ; v_pk_add_u16 acc,acc,d
// Opaque-zero VGPR offset keeps LDS reads inside the pass loop (no CSE).

#define T_DIM   256
#define C_DIM   16
#define NB      64
#define TC      4096
#define CHUNKS  16
#define BBLK    128
#define KPT     8
#define PITCH32 68             // xs row pitch in u32 b-pairs (64 + 4 pad)
#define PASSES  4              // redundant passes for the slope test

typedef _Float16 h2_t __attribute__((ext_vector_type(2)));

static __device__ __forceinline__ unsigned pack2f16(float v) {
    h2_t p; p.x = (_Float16)v; p.y = p.x;
    return __builtin_bit_cast(unsigned, p);
}

__global__ __launch_bounds__(256, 8) void histo_count_kernel(
    const float* __restrict__ x,       // [1024, 4096]
    const float* __restrict__ locs,    // [4096, 64]
    const float* __restrict__ deltas,  // [4096]
    unsigned char* __restrict__ counts,// [CHUNKS][4096][64] u8
    float* __restrict__ out)           // [1] (zeroed for k2's atomics)
{
    __shared__ unsigned xs32[C_DIM * PITCH32];   // 16 x 68 u32 = 4352 B
    const int tid   = threadIdx.x;
    const int t     = blockIdx.x & 255;
    const int chunk = blockIdx.x >> 8;           // 0..7 (128 b each)

    if (blockIdx.x == 0 && tid == 0) out[0] = 0.0f;

    // Stage x[chunk*128 .. +127][t*16 .. +15] -> fp16 b-pairs in u32.
    {
        const int bpair = tid >> 2;              // 0..63
        const int c4    = (tid & 3) * 4;
        const float* r0 = x + (size_t)(chunk * BBLK + 2 * bpair) * TC + t * C_DIM + c4;
        const float4 va = *(const float4*)r0;
        const float4 vb = *(const float4*)(r0 + TC);
        const float a[4] = {va.x, va.y, va.z, va.w};
        const float b[4] = {vb.x, vb.y, vb.z, vb.w};
#pragma unroll
        for (int k = 0; k < 4; ++k) {
            h2_t p;
            p.x = (_Float16)a[k];
            p.y = (_Float16)b[k];
            xs32[(c4 + k) * PITCH32 + bpair] = __builtin_bit_cast(unsigned, p);
        }
    }

    const int bg = tid >> 7;           // b-subgroup: 64 b's each
    const int r  = tid & 127;
    const int c  = r >> 3;             // 0..15
    const int kq = r & 7;              // bins [kq*8, kq*8+8)
    const int tc = t * C_DIM + c;

    const float hf = 0.5f * deltas[tc];
    const unsigned nh = pack2f16(-hf);           // (-h, -h)

    unsigned nl[KPT];
    const float* lp = locs + (size_t)tc * NB + kq * KPT;
#pragma unroll
    for (int j = 0; j < KPT; ++j)
        nl[j] = pack2f16(-lp[j]);                // (-l, -l)

    unsigned acc[KPT];
#pragma unroll
    for (int j = 0; j < KPT; ++j) acc[j] = 0u;

    const unsigned sh15 = 0x000F000Fu;           // per-half shift amount 15

    __syncthreads();

    const uint4* xr = (const uint4*)(xs32 + c * PITCH32 + bg * 32);

    // PASSES identical passes; acc accumulates 4x the true counts
    // (halves <= 128, u16-safe); final >>2 restores exact counts.
#pragma unroll 1
    for (int pass = 0; pass < PASSES; ++pass) {
        // Opaque zero: compiler can't prove the LDS reads repeat -> loads
        // stay inside the pass loop, no cross-pass CSE / register blowup.
        unsigned zoff;
        asm volatile("v_mov_b32 %0, 0" : "=v"(zoff));
        const uint4* xrp = xr + zoff;
#pragma unroll 2
        for (int g = 0; g < 8; ++g) {
            const uint4 u = xrp[g];
            const unsigned up[4] = {u.x, u.y, u.z, u.w};
#pragma unroll
            for (int j = 0; j < KPT; ++j) {
#pragma unroll
                for (int q = 0; q < 4; ++q) {
                    unsigned tmp;
                    asm("v_pk_add_f16 %0, %2, %3\n\t"
                        "v_and_b32 %0, 0x7fff7fff, %0\n\t"
                        "v_pk_add_f16 %0, %0, %4\n\t"
                        "v_pk_lshrrev_b16 %0, %5, %0\n\t"
                        "v_pk_add_u16 %1, %1, %0"
                        : "=&v"(tmp), "+v"(acc[j])
                        : "v"(up[q]), "v"(nl[j]), "v"(nh), "v"(sh15));
                }
            }
        }
    }

    unsigned long long pack = 0;
#pragma unroll
    for (int j = 0; j < KPT; ++j) {
        const unsigned cj = (((acc[j] & 0xffffu) + (acc[j] >> 16)) >> 2);  // /4 exact
        pack |= (unsigned long long)cj << (8 * j);
    }
    *(unsigned long long*)(counts + (size_t)(chunk * 2 + bg) * (TC * NB)
                                  + (size_t)tc * NB + kq * KPT) = pack;
}

__global__ __launch_bounds__(256) void histo_loss_kernel(
    const unsigned char* __restrict__ counts, // [CHUNKS][4096][64]
    const float* __restrict__ deltas,         // [4096]
    const float* __restrict__ dens,           // [4096, 64]
    float* __restrict__ out)                  // [1]
{
    const int gid = blockIdx.x * 256 + threadIdx.x;
    const int i0  = gid * 4;                  // 4 consecutive items, same tc

    int cnt[4] = {0, 0, 0, 0};
#pragma unroll
    for (int ch = 0; ch < CHUNKS; ++ch) {
        const unsigned u = *(const unsigned*)(counts + (size_t)ch * (TC * NB) + i0);
#pragma unroll
        for (int q = 0; q < 4; ++q)
            cnt[q] += (int)((u >> (8 * q)) & 0xffu);
    }

    const float delta = deltas[i0 >> 6];
    const float4 dv = *(const float4*)(dens + i0);
    // Reference order: (cnt/1024) exact, then / delta.
    float s = fabsf((cnt[0] * (1.0f / 1024.0f)) / delta - dv.x)
            + fabsf((cnt[1] * (1.0f / 1024.0f)) / delta - dv.y)
            + fabsf((cnt[2] * (1.0f / 1024.0f)) / delta - dv.z)
            + fabsf((cnt[3] * (1.0f / 1024.0f)) / delta - dv.w);

#pragma unroll
    for (int off = 32; off > 0; off >>= 1)
        s += __shfl_down(s, off, 64);

    __shared__ float sb[4];
    if ((threadIdx.x & 63) == 0) sb[threadIdx.x >> 6] = s;
    __syncthreads();

    if (threadIdx.x == 0)   // REG * mean over (t,c,k) = sum / 262144
        atomicAdd(out, (sb[0] + sb[1] + sb[2] + sb[3]) * (1.0f / 262144.0f));
}

extern "C" void kernel_launch(void* const* d_in, const int* in_sizes, int n_in,
                              void* d_out, int out_size, void* d_ws, size_t ws_size,
                              hipStream_t stream) {
    const float* x      = (const float*)d_in[0];  // x_fake    [1024,256,16]
    const float* locs   = (const float*)d_in[1];  // locs      [256,16,64]
    const float* deltas = (const float*)d_in[2];  // deltas    [256,16]
    const float* dens   = (const float*)d_in[3];  // densities [256,16,64]
    float* out = (float*)d_out;
    unsigned char* cnts = (unsigned char*)d_ws;   // 4 MB scratch

    histo_count_kernel<<<T_DIM * 8, 256, 0, stream>>>(x, locs, deltas, cnts, out);
    histo_loss_kernel<<<(TC * NB) / (256 * 4), 256, 0, stream>>>(cnts, deltas, dens, out);
}

// Round 11
// 92.422 us; speedup vs baseline: 1.5711x; 1.5711x over previous
//
#include <hip/hip_runtime.h>

// HistoLoss: B=1024, T=256, C=16, NB=64; TC=4096; x flat = [b][tc]
//
// Round-10 slope test (4x redundant passes): k1(1x) = 30.4 us = 17.8 compute
// + 12.6 non-compute; ideal issue = 8.5 us (2.1x gap); occupancy pinned at
// ~16 waves/CU (~4 waves/SIMD) in every config -> serial 5-inst asm chains
// (4 cyc spacing) under-issue at 4 waves. Round-11:
//  (a) persistent 2-tile blocks, double-buffered LDS: grid 1024 = 4 blk/CU;
//      next tile's global loads fly behind current tile's compute; locs/
//      deltas loaded once per block (same tc across tiles) -> attacks 12.6us.
//  (b) dual-chain asm (2 independent 5-inst chains interleaved, spacing 2)
//      -> single-wave issue ~1/2cyc -> attacks the 2.1x issue gap.
// Inner math unchanged (validated R5/R7/R9, absmax 0): packed fp16 sign-bit
// counting, 5 inst / 2 indicators, exact u16 counts.

#define T_DIM   256
#define C_DIM   16
#define NB      64
#define TC      4096
#define CHUNKS  16
#define BBLK    128            // b per tile
#define KPT     8
#define PITCH32 68             // LDS row pitch in u32 b-pairs (64 + 4 pad)
#define NT      2              // tiles (chunks) per block

typedef _Float16 h2_t __attribute__((ext_vector_type(2)));

static __device__ __forceinline__ unsigned pack2f16(float v) {
    h2_t p; p.x = (_Float16)v; p.y = p.x;
    return __builtin_bit_cast(unsigned, p);
}

__global__ __launch_bounds__(256, 8) void histo_count_kernel(
    const float* __restrict__ x,       // [1024, 4096]
    const float* __restrict__ locs,    // [4096, 64]
    const float* __restrict__ deltas,  // [4096]
    unsigned char* __restrict__ counts,// [CHUNKS][4096][64] u8
    float* __restrict__ out)           // [1] (zeroed for k2's atomics)
{
    __shared__ unsigned xs32[2][C_DIM * PITCH32];   // 2 x 4352 B
    const int tid  = threadIdx.x;
    const int t    = blockIdx.x & 255;
    const int pair = blockIdx.x >> 8;               // 0..3 -> chunks {2p, 2p+1}

    if (blockIdx.x == 0 && tid == 0) out[0] = 0.0f;

    // --- thread roles ---
    const int bpair = tid >> 2;            // staging: b-pair 0..63
    const int c4    = (tid & 3) * 4;       // staging: c offset
    const int bg    = tid >> 7;            // compute: b-subgroup (64 b's)
    const int r     = tid & 127;
    const int c     = r >> 3;              // 0..15
    const int kq    = r & 7;               // bins [kq*8, kq*8+8)
    const int tc    = t * C_DIM + c;

    // --- per-block constants (identical for both tiles: same t) ---
    const float hf = 0.5f * deltas[tc];
    const unsigned nh = pack2f16(-hf);
    unsigned nl[KPT];
    const float* lp = locs + (size_t)tc * NB + kq * KPT;
#pragma unroll
    for (int j = 0; j < KPT; ++j) nl[j] = pack2f16(-lp[j]);
    const unsigned sh15 = 0x000F000Fu;

    // --- prologue: stage tile 0 ---
    const float* r0 = x + (size_t)(pair * NT * BBLK + 2 * bpair) * TC + t * C_DIM + c4;
    float4 va = *(const float4*)r0;
    float4 vb = *(const float4*)(r0 + TC);
    {
        const float a[4] = {va.x, va.y, va.z, va.w};
        const float b[4] = {vb.x, vb.y, vb.z, vb.w};
#pragma unroll
        for (int k = 0; k < 4; ++k) {
            h2_t p; p.x = (_Float16)a[k]; p.y = (_Float16)b[k];
            xs32[0][(c4 + k) * PITCH32 + bpair] = __builtin_bit_cast(unsigned, p);
        }
    }
    __syncthreads();

#pragma unroll
    for (int ti = 0; ti < NT; ++ti) {
        // Prefetch next tile's globals -> regs; they fly behind compute.
        if (ti + 1 < NT) {
            const float* r1 = r0 + (size_t)(ti + 1) * BBLK * TC;
            va = *(const float4*)r1;
            vb = *(const float4*)(r1 + TC);
        }

        // Compute tile ti from xs32[ti&1].
        unsigned acc[KPT];
#pragma unroll
        for (int j = 0; j < KPT; ++j) acc[j] = 0u;

        const uint4* xr = (const uint4*)(&xs32[ti & 1][c * PITCH32 + bg * 32]);
#pragma unroll 2
        for (int g = 0; g < 8; ++g) {
            const uint4 u = xr[g];
#pragma unroll
            for (int j = 0; j < KPT; ++j) {
                unsigned t0, t1;
                // Two independent 5-inst chains, interleaved (spacing 2):
                // per chain: pk_add(-l); and 0x7fff7fff; pk_add(-h);
                // pk_lshr 15 (0/1 halves); pk_add_u16 into acc.
                asm("v_pk_add_f16 %0, %3, %5\n\t"
                    "v_pk_add_f16 %1, %4, %5\n\t"
                    "v_and_b32 %0, 0x7fff7fff, %0\n\t"
                    "v_and_b32 %1, 0x7fff7fff, %1\n\t"
                    "v_pk_add_f16 %0, %0, %6\n\t"
                    "v_pk_add_f16 %1, %1, %6\n\t"
                    "v_pk_lshrrev_b16 %0, %7, %0\n\t"
                    "v_pk_lshrrev_b16 %1, %7, %1\n\t"
                    "v_pk_add_u16 %2, %2, %0\n\t"
                    "v_pk_add_u16 %2, %2, %1"
                    : "=&v"(t0), "=&v"(t1), "+v"(acc[j])
                    : "v"(u.x), "v"(u.y), "v"(nl[j]), "v"(nh), "v"(sh15));
                asm("v_pk_add_f16 %0, %3, %5\n\t"
                    "v_pk_add_f16 %1, %4, %5\n\t"
                    "v_and_b32 %0, 0x7fff7fff, %0\n\t"
                    "v_and_b32 %1, 0x7fff7fff, %1\n\t"
                    "v_pk_add_f16 %0, %0, %6\n\t"
                    "v_pk_add_f16 %1, %1, %6\n\t"
                    "v_pk_lshrrev_b16 %0, %7, %0\n\t"
                    "v_pk_lshrrev_b16 %1, %7, %1\n\t"
                    "v_pk_add_u16 %2, %2, %0\n\t"
                    "v_pk_add_u16 %2, %2, %1"
                    : "=&v"(t0), "=&v"(t1), "+v"(acc[j])
                    : "v"(u.z), "v"(u.w), "v"(nl[j]), "v"(nh), "v"(sh15));
            }
        }

        // Store tile ti's counts (chunk = pair*NT + ti).
        unsigned long long pack = 0;
#pragma unroll
        for (int j = 0; j < KPT; ++j) {
            const unsigned cj = (acc[j] & 0xffffu) + (acc[j] >> 16);  // <=64 exact
            pack |= (unsigned long long)cj << (8 * j);
        }
        const int chunk = pair * NT + ti;
        *(unsigned long long*)(counts + (size_t)(chunk * 2 + bg) * (TC * NB)
                                      + (size_t)tc * NB + kq * KPT) = pack;

        // Write next tile into the other LDS buffer; safe: its readers all
        // passed the previous barrier. One barrier per tile.
        if (ti + 1 < NT) {
            const float a[4] = {va.x, va.y, va.z, va.w};
            const float b[4] = {vb.x, vb.y, vb.z, vb.w};
#pragma unroll
            for (int k = 0; k < 4; ++k) {
                h2_t p; p.x = (_Float16)a[k]; p.y = (_Float16)b[k];
                xs32[(ti + 1) & 1][(c4 + k) * PITCH32 + bpair] =
                    __builtin_bit_cast(unsigned, p);
            }
            __syncthreads();
        }
    }
}

__global__ __launch_bounds__(256) void histo_loss_kernel(
    const unsigned char* __restrict__ counts, // [CHUNKS][4096][64]
    const float* __restrict__ deltas,         // [4096]
    const float* __restrict__ dens,           // [4096, 64]
    float* __restrict__ out)                  // [1]
{
    const int gid = blockIdx.x * 256 + threadIdx.x;
    const int i0  = gid * 4;                  // 4 consecutive items, same tc

    int cnt[4] = {0, 0, 0, 0};
#pragma unroll
    for (int ch = 0; ch < CHUNKS; ++ch) {
        const unsigned u = *(const unsigned*)(counts + (size_t)ch * (TC * NB) + i0);
#pragma unroll
        for (int q = 0; q < 4; ++q)
            cnt[q] += (int)((u >> (8 * q)) & 0xffu);
    }

    const float delta = deltas[i0 >> 6];
    const float4 dv = *(const float4*)(dens + i0);
    // Reference order: (cnt/1024) exact, then / delta.
    float s = fabsf((cnt[0] * (1.0f / 1024.0f)) / delta - dv.x)
            + fabsf((cnt[1] * (1.0f / 1024.0f)) / delta - dv.y)
            + fabsf((cnt[2] * (1.0f / 1024.0f)) / delta - dv.z)
            + fabsf((cnt[3] * (1.0f / 1024.0f)) / delta - dv.w);

#pragma unroll
    for (int off = 32; off > 0; off >>= 1)
        s += __shfl_down(s, off, 64);

    __shared__ float sb[4];
    if ((threadIdx.x & 63) == 0) sb[threadIdx.x >> 6] = s;
    __syncthreads();

    if (threadIdx.x == 0)   // REG * mean over (t,c,k) = sum / 262144
        atomicAdd(out, (sb[0] + sb[1] + sb[2] + sb[3]) * (1.0f / 262144.0f));
}

extern "C" void kernel_launch(void* const* d_in, const int* in_sizes, int n_in,
                              void* d_out, int out_size, void* d_ws, size_t ws_size,
                              hipStream_t stream) {
    const float* x      = (const float*)d_in[0];  // x_fake    [1024,256,16]
    const float* locs   = (const float*)d_in[1];  // locs      [256,16,64]
    const float* deltas = (const float*)d_in[2];  // deltas    [256,16]
    const float* dens   = (const float*)d_in[3];  // densities [256,16,64]
    float* out = (float*)d_out;
    unsigned char* cnts = (unsigned char*)d_ws;   // 4 MB scratch

    histo_count_kernel<<<T_DIM * (8 / NT), 256, 0, stream>>>(x, locs, deltas, cnts, out);
    histo_loss_kernel<<<(TC * NB) / (256 * 4), 256, 0, stream>>>(cnts, deltas, dens, out);
}

// Round 12
// 89.958 us; speedup vs baseline: 1.6141x; 1.0274x over previous
//
#include <hip/hip_runtime.h>

// HistoLoss: B=1024, T=256, C=16, NB=64; TC=4096; x flat = [b][tc]
//
// Round-11 falsified latency-bound theory (dual-chain ILP: no change) ->
// VOP3P v_pk_* ops are ~half-rate (~4cyc) on gfx950; all prior variants were
// ~10-14 cyc/indicator regardless of source. Round-12: integer range-check
// in plain VOP2 (measured-full-rate class, m07), 3 inst / indicator:
//   v_sub_u32 t, xi, qlo ; v_cmp_lt_u32 vcc, t, qw ; v_addc acc, vcc
// Fixed-point x4096 (i32): boundary fuzz +-1.2e-4 in x-space, smaller than
// the fp16 fuzz (5e-4) already validated in R5/R7/R9 (absmax 0.0).
// Target: 6 cyc/ind -> compute 17.8 -> ~10us, k1 ~22-24us, total ~85.
//
// k1: 256 thr = 2 b-subgroups x (16 c x 8 kq); block = (t, 128-b chunk);
//     grid 2048. x staged as i32 fixed-point, rows xsi[c][132] (4-bank
//     disjoint spans/wave, 8-way broadcast: conflict-free ds_read_b128).
//     Counts exact ints <= 64 -> u8 pack -> one 8B store. Line-exact fetch.
// k2: sum 16 chunk u8s, loss, block-reduce, one atomicAdd/block (out[0]
//     zeroed by k1 block 0; stream-ordered). Harness fixed cost ~61us
//     (43.5us 256MB ws re-poison + restores + gaps) — immovable.

#define T_DIM   256
#define C_DIM   16
#define NB      64
#define TC      4096
#define CHUNKS  16
#define BBLK    128
#define KPT     8
#define PITCHI  132            // xsi row pitch in i32 (128 + 4 pad)
#define QSCALE  4096.0f        // fixed-point scale (x in ~[-4,4] -> |xi|<2^15)

__global__ __launch_bounds__(256, 8) void histo_count_kernel(
    const float* __restrict__ x,       // [1024, 4096]
    const float* __restrict__ locs,    // [4096, 64]
    const float* __restrict__ deltas,  // [4096]
    unsigned char* __restrict__ counts,// [CHUNKS][4096][64] u8
    float* __restrict__ out)           // [1] (zeroed for k2's atomics)
{
    __shared__ int xsi[C_DIM * PITCHI];          // 16 x 132 i32 = 8448 B
    const int tid   = threadIdx.x;
    const int t     = blockIdx.x & 255;
    const int chunk = blockIdx.x >> 8;           // 0..7 (128 b each)

    if (blockIdx.x == 0 && tid == 0) out[0] = 0.0f;

    // Stage x[chunk*128 .. +127][t*16 .. +15] -> i32 fixed-point (x*4096).
    // Thread (bpair = tid>>2, c4 = (tid&3)*4): two float4 rows (b, b+1);
    // 4 threads cover each 64B line exactly once. 8 i32 LDS writes.
    {
        const int bpair = tid >> 2;              // 0..63
        const int c4    = (tid & 3) * 4;
        const int b0    = 2 * bpair;
        const float* r0 = x + (size_t)(chunk * BBLK + b0) * TC + t * C_DIM + c4;
        const float4 va = *(const float4*)r0;
        const float4 vb = *(const float4*)(r0 + TC);
        const float a[4] = {va.x, va.y, va.z, va.w};
        const float b[4] = {vb.x, vb.y, vb.z, vb.w};
#pragma unroll
        for (int k = 0; k < 4; ++k) {
            xsi[(c4 + k) * PITCHI + b0]     = (int)__float2int_rn(a[k] * QSCALE);
            xsi[(c4 + k) * PITCHI + b0 + 1] = (int)__float2int_rn(b[k] * QSCALE);
        }
    }

    const int bg = tid >> 7;           // b-subgroup: 64 b's each
    const int r  = tid & 127;
    const int c  = r >> 3;             // 0..15
    const int kq = r & 7;              // bins [kq*8, kq*8+8)
    const int tc = t * C_DIM + c;

    const float hf = 0.5f * deltas[tc];
    const int   qw = __float2int_rn(2.0f * hf * QSCALE);   // window width

    int qlo[KPT];
    const float* lp = locs + (size_t)tc * NB + kq * KPT;
#pragma unroll
    for (int j = 0; j < KPT; ++j)
        qlo[j] = __float2int_rn((lp[j] - hf) * QSCALE);    // window low edge

    int acc[KPT];
#pragma unroll
    for (int j = 0; j < KPT; ++j) acc[j] = 0;

    __syncthreads();

    // 16 iters x (1 ds_read_b128 = 4 xi) x 8 bins x 4 x 3 VOP2 inst.
    // All full-rate (2 cyc) ops; vcc chains issue back-to-back in order.
    const int4* xr = (const int4*)(xsi + c * PITCHI + bg * 64);
#pragma unroll 4
    for (int g = 0; g < 16; ++g) {
        const int4 u = xr[g];
        const int xi[4] = {u.x, u.y, u.z, u.w};
#pragma unroll
        for (int j = 0; j < KPT; ++j) {
#pragma unroll
            for (int q = 0; q < 4; ++q) {
                int tmp;
                asm("v_sub_u32 %0, %2, %3\n\t"
                    "v_cmp_lt_u32 vcc, %0, %4\n\t"
                    "v_addc_co_u32 %1, vcc, 0, %1, vcc"
                    : "=&v"(tmp), "+v"(acc[j])
                    : "v"(xi[q]), "v"(qlo[j]), "v"(qw)
                    : "vcc");
            }
        }
    }

    unsigned long long pack = 0;
#pragma unroll
    for (int j = 0; j < KPT; ++j)
        pack |= (unsigned long long)(unsigned)acc[j] << (8 * j);  // <=64 each
    *(unsigned long long*)(counts + (size_t)(chunk * 2 + bg) * (TC * NB)
                                  + (size_t)tc * NB + kq * KPT) = pack;
}

__global__ __launch_bounds__(256) void histo_loss_kernel(
    const unsigned char* __restrict__ counts, // [CHUNKS][4096][64]
    const float* __restrict__ deltas,         // [4096]
    const float* __restrict__ dens,           // [4096, 64]
    float* __restrict__ out)                  // [1]
{
    const int gid = blockIdx.x * 256 + threadIdx.x;
    const int i0  = gid * 4;                  // 4 consecutive items, same tc

    int cnt[4] = {0, 0, 0, 0};
#pragma unroll
    for (int ch = 0; ch < CHUNKS; ++ch) {
        const unsigned u = *(const unsigned*)(counts + (size_t)ch * (TC * NB) + i0);
#pragma unroll
        for (int q = 0; q < 4; ++q)
            cnt[q] += (int)((u >> (8 * q)) & 0xffu);
    }

    const float delta = deltas[i0 >> 6];
    const float4 dv = *(const float4*)(dens + i0);
    // Reference order: (cnt/1024) exact, then / delta.
    float s = fabsf((cnt[0] * (1.0f / 1024.0f)) / delta - dv.x)
            + fabsf((cnt[1] * (1.0f / 1024.0f)) / delta - dv.y)
            + fabsf((cnt[2] * (1.0f / 1024.0f)) / delta - dv.z)
            + fabsf((cnt[3] * (1.0f / 1024.0f)) / delta - dv.w);

#pragma unroll
    for (int off = 32; off > 0; off >>= 1)
        s += __shfl_down(s, off, 64);

    __shared__ float sb[4];
    if ((threadIdx.x & 63) == 0) sb[threadIdx.x >> 6] = s;
    __syncthreads();

    if (threadIdx.x == 0)   // REG * mean over (t,c,k) = sum / 262144
        atomicAdd(out, (sb[0] + sb[1] + sb[2] + sb[3]) * (1.0f / 262144.0f));
}

extern "C" void kernel_launch(void* const* d_in, const int* in_sizes, int n_in,
                              void* d_out, int out_size, void* d_ws, size_t ws_size,
                              hipStream_t stream) {
    const float* x      = (const float*)d_in[0];  // x_fake    [1024,256,16]
    const float* locs   = (const float*)d_in[1];  // locs      [256,16,64]
    const float* deltas = (const float*)d_in[2];  // deltas    [256,16]
    const float* dens   = (const float*)d_in[3];  // densities [256,16,64]
    float* out = (float*)d_out;
    unsigned char* cnts = (unsigned char*)d_ws;   // 4 MB scratch

    histo_count_kernel<<<T_DIM * 8, 256, 0, stream>>>(x, locs, deltas, cnts, out);
    histo_loss_kernel<<<(TC * NB) / (256 * 4), 256, 0, stream>>>(cnts, deltas, dens, out);
}